// Round 4
// baseline (124.511 us; speedup 1.0000x reference)
//
#include <hip/hip_runtime.h>
#include <cstdint>
#include <cstddef>

#define BATCH 8
#define SEQ 1024
#define DIM 768
#define EPS_K 1e-7f

typedef __bf16 bf16x8 __attribute__((ext_vector_type(8)));
typedef float f32x4 __attribute__((ext_vector_type(4)));
typedef uint16_t u16x8 __attribute__((ext_vector_type(8)));

__device__ __forceinline__ uint16_t f2bf(float f) {
  union { float f; uint32_t u; } v; v.f = f;
  uint32_t u = v.u;
  u += 0x7FFFu + ((u >> 16) & 1u);   // RNE to bf16
  return (uint16_t)(u >> 16);
}

__device__ __forceinline__ void gload16(const void* g, void* l) {
  __builtin_amdgcn_global_load_lds(
      (const __attribute__((address_space(1))) uint32_t*)g,
      (__attribute__((address_space(3))) uint32_t*)l, 16, 0, 0);
}

// ---------------------------------------------------------------------------
// Kernel 1: fp32 -> bf16 convert (vectorized): ab[b][s][d] row-major and
// at[b][d][s] transposed.  float4 loads, short8 stores.
// ---------------------------------------------------------------------------
__global__ __launch_bounds__(256) void convert_kernel(const float* __restrict__ A,
                                                      uint16_t* __restrict__ ab,
                                                      uint16_t* __restrict__ at) {
  const int b  = blockIdx.z;
  const int s0 = blockIdx.y * 64;
  const int d0 = blockIdx.x * 64;
  __shared__ uint16_t tl[64][80];            // 160B row stride (16B-aligned)
  const int tid = threadIdx.x;

  // phase 1: 2 rounds, each thread converts 8 consecutive d of one s-row
#pragma unroll
  for (int i = 0; i < 2; ++i) {
    const int sl = (tid >> 3) + i * 32;      // 0..63
    const int ch = tid & 7;                  // 8-elem chunk
    const float* src = A + ((size_t)b * SEQ + s0 + sl) * DIM + d0 + ch * 8;
    float4 f0 = *(const float4*)src;
    float4 f1 = *(const float4*)(src + 4);
    u16x8 h;
    h[0] = f2bf(f0.x); h[1] = f2bf(f0.y); h[2] = f2bf(f0.z); h[3] = f2bf(f0.w);
    h[4] = f2bf(f1.x); h[5] = f2bf(f1.y); h[6] = f2bf(f1.z); h[7] = f2bf(f1.w);
    *(u16x8*)&ab[((size_t)b * SEQ + s0 + sl) * DIM + d0 + ch * 8] = h;
    *(u16x8*)&tl[sl][ch * 8] = h;
  }
  __syncthreads();
  // phase 2: transpose out of LDS, short8 along s
  const int dl = tid >> 2;                   // 0..63
#pragma unroll
  for (int i = 0; i < 2; ++i) {
    const int sc = (tid & 3) + i * 4;        // 0..7
    u16x8 h;
#pragma unroll
    for (int e = 0; e < 8; ++e) h[e] = tl[sc * 8 + e][dl];
    *(u16x8*)&at[((size_t)b * DIM + d0 + dl) * SEQ + s0 + sc * 8] = h;
  }
}

// ---------------------------------------------------------------------------
// GEMM geometry shared by kernels 2 & 3:
//   BM=256, BN=128, BK=64, 8 waves as 4x2, per-wave C = 64x64 (4x4 frags).
//   LDS: A[2][256][64] + B[2][128][64] bf16 = 96 KB, 1 block/CU.
//   T2 swizzle: 16B chunk index ^= (row&7); LDS dest linear (gload_lds),
//   global SOURCE pre-swizzled, ds_read applies same XOR (rule #21).
//   T4: counted s_waitcnt vmcnt(6) + raw s_barrier (never drain in loop).
//   T5: setprio around MFMA cluster.
// ---------------------------------------------------------------------------

// ---------------------------------------------------------------------------
// Kernel 2: P[b][q][t] = m_q*m_t*exp(ab[q]·ab[t])  (bf16)
// grid: bid&7 = batch (XCD pin), tile = bid>>3: s0 = (tile>>3)*256, t0=(tile&7)*128
// ---------------------------------------------------------------------------
__global__ __launch_bounds__(512, 2) void scores_kernel(const uint16_t* __restrict__ ab,
                                                        const int* __restrict__ mask,
                                                        uint16_t* __restrict__ P) {
  const int b    = blockIdx.x & 7;
  const int tile = blockIdx.x >> 3;          // 0..31
  const int s0   = (tile >> 3) * 256;
  const int t0   = (tile & 7) * 128;

  const int tid  = threadIdx.x;
  const int lane = tid & 63;
  const int wid  = tid >> 6;
  const int wr   = wid >> 1;                 // 0..3  (m)
  const int wc   = wid & 1;                  // 0..1  (n)

  __shared__ __align__(16) uint16_t lA[2][256 * 64];   // 64 KB
  __shared__ __align__(16) uint16_t lB[2][128 * 64];   // 32 KB

  const uint16_t* gA = ab + ((size_t)b * SEQ + s0) * DIM;
  const uint16_t* gB = ab + ((size_t)b * SEQ + t0) * DIM;

  const int srl  = tid >> 3;                            // staging row 0..63
  const int schx = ((tid & 7) ^ (srl & 7)) << 3;        // pre-swizzled src col
  const int sdst = srl * 64 + (tid & 7) * 8;            // linear LDS dest

#define STAGE(buf, k0)                                                         \
  do {                                                                         \
    _Pragma("unroll")                                                          \
    for (int _i = 0; _i < 4; ++_i)                                             \
      gload16(gA + (size_t)(srl + _i * 64) * DIM + (k0) + schx,                \
              &lA[buf][sdst + _i * 64 * 64]);                                  \
    _Pragma("unroll")                                                          \
    for (int _i = 0; _i < 2; ++_i)                                             \
      gload16(gB + (size_t)(srl + _i * 64) * DIM + (k0) + schx,                \
              &lB[buf][sdst + _i * 64 * 64]);                                  \
  } while (0)

  f32x4 acc[4][4];
#pragma unroll
  for (int m = 0; m < 4; ++m)
#pragma unroll
    for (int n = 0; n < 4; ++n) acc[m][n] = f32x4{0.f, 0.f, 0.f, 0.f};

  const int rA  = wr * 64 + (lane & 15);
  const int rB  = wc * 64 + (lane & 15);
  const int cx0 = (((lane >> 4) + 0) ^ (lane & 7)) << 3;   // kk=0 chunk (swz)
  const int cx1 = (((lane >> 4) + 4) ^ (lane & 7)) << 3;   // kk=1 chunk (swz)

  STAGE(0, 0);
  int cur = 0;
  for (int t = 0; t < DIM / 64; ++t) {
    if (t + 1 < DIM / 64) {
      STAGE(cur ^ 1, (t + 1) * 64);
      asm volatile("s_waitcnt vmcnt(6)" ::: "memory");   // this tile landed
    } else {
      asm volatile("s_waitcnt vmcnt(0)" ::: "memory");
    }
    __builtin_amdgcn_s_barrier();

    bf16x8 bfr[2][4];
#pragma unroll
    for (int n = 0; n < 4; ++n) {
      bfr[0][n] = *(const bf16x8*)&lB[cur][(rB + n * 16) * 64 + cx0];
      bfr[1][n] = *(const bf16x8*)&lB[cur][(rB + n * 16) * 64 + cx1];
    }
    __builtin_amdgcn_s_setprio(1);
#pragma unroll
    for (int m = 0; m < 4; ++m) {
      bf16x8 a0 = *(const bf16x8*)&lA[cur][(rA + m * 16) * 64 + cx0];
      bf16x8 a1 = *(const bf16x8*)&lA[cur][(rA + m * 16) * 64 + cx1];
#pragma unroll
      for (int n = 0; n < 4; ++n) {
        acc[m][n] = __builtin_amdgcn_mfma_f32_16x16x32_bf16(a0, bfr[0][n], acc[m][n], 0, 0, 0);
        acc[m][n] = __builtin_amdgcn_mfma_f32_16x16x32_bf16(a1, bfr[1][n], acc[m][n], 0, 0, 0);
      }
    }
    __builtin_amdgcn_s_setprio(0);
    __builtin_amdgcn_s_barrier();            // all done reading buf[cur]
    cur ^= 1;
  }
#undef STAGE

  // Epilogue: e = exp(S)*m_q*m_t, bf16 store. Mask read direct from global.
  const int* mk = mask + b * SEQ;
  uint16_t* Pb = P + (size_t)b * SEQ * SEQ;
  float mc[4];
#pragma unroll
  for (int n = 0; n < 4; ++n) mc[n] = (float)mk[t0 + wc * 64 + n * 16 + (lane & 15)];
#pragma unroll
  for (int m = 0; m < 4; ++m) {
#pragma unroll
    for (int j = 0; j < 4; ++j) {
      const int rs = s0 + wr * 64 + m * 16 + (lane >> 4) * 4 + j;
      const float mr = (float)mk[rs];
#pragma unroll
      for (int n = 0; n < 4; ++n) {
        const int ct = t0 + wc * 64 + n * 16 + (lane & 15);
        float e = __expf(acc[m][n][j]) * mr * mc[n];
        Pb[(size_t)rs * SEQ + ct] = f2bf(e);
      }
    }
  }
}

// ---------------------------------------------------------------------------
// Kernel 3: out[b][q][d] = sum_t P[q][t]*at[d][t] / (den_q+eps),
// den via ones-B MFMA (row-sum in matching C-layout).
// grid: bid&7 = batch; tile = bid>>3 in [0,24): q0=(tile/6)*256, d0=(tile%6)*128
// ---------------------------------------------------------------------------
__global__ __launch_bounds__(512, 2) void out_kernel(const uint16_t* __restrict__ P,
                                                     const uint16_t* __restrict__ at,
                                                     float* __restrict__ out) {
  const int b    = blockIdx.x & 7;
  const int tile = blockIdx.x >> 3;          // 0..23
  const int q0   = (tile / 6) * 256;
  const int d0   = (tile % 6) * 128;

  const int tid  = threadIdx.x;
  const int lane = tid & 63;
  const int wid  = tid >> 6;
  const int wr   = wid >> 1;
  const int wc   = wid & 1;

  __shared__ __align__(16) uint16_t lA[2][256 * 64];   // P tile
  __shared__ __align__(16) uint16_t lB[2][128 * 64];   // at tile

  const uint16_t* gA = P  + ((size_t)b * SEQ + q0) * SEQ;
  const uint16_t* gB = at + ((size_t)b * DIM + d0) * SEQ;

  const int srl  = tid >> 3;
  const int schx = ((tid & 7) ^ (srl & 7)) << 3;
  const int sdst = srl * 64 + (tid & 7) * 8;

#define STAGE(buf, k0)                                                         \
  do {                                                                         \
    _Pragma("unroll")                                                          \
    for (int _i = 0; _i < 4; ++_i)                                             \
      gload16(gA + (size_t)(srl + _i * 64) * SEQ + (k0) + schx,                \
              &lA[buf][sdst + _i * 64 * 64]);                                  \
    _Pragma("unroll")                                                          \
    for (int _i = 0; _i < 2; ++_i)                                             \
      gload16(gB + (size_t)(srl + _i * 64) * SEQ + (k0) + schx,                \
              &lB[buf][sdst + _i * 64 * 64]);                                  \
  } while (0)

  f32x4 acc[4][4];
  f32x4 accd[4];
#pragma unroll
  for (int m = 0; m < 4; ++m) {
    accd[m] = f32x4{0.f, 0.f, 0.f, 0.f};
#pragma unroll
    for (int n = 0; n < 4; ++n) acc[m][n] = f32x4{0.f, 0.f, 0.f, 0.f};
  }
  bf16x8 ones;
#pragma unroll
  for (int i = 0; i < 8; ++i) ones[i] = (__bf16)1.0f;

  const int rA  = wr * 64 + (lane & 15);
  const int rB  = wc * 64 + (lane & 15);
  const int cx0 = (((lane >> 4) + 0) ^ (lane & 7)) << 3;
  const int cx1 = (((lane >> 4) + 4) ^ (lane & 7)) << 3;

  STAGE(0, 0);
  int cur = 0;
  for (int t = 0; t < SEQ / 64; ++t) {
    if (t + 1 < SEQ / 64) {
      STAGE(cur ^ 1, (t + 1) * 64);
      asm volatile("s_waitcnt vmcnt(6)" ::: "memory");
    } else {
      asm volatile("s_waitcnt vmcnt(0)" ::: "memory");
    }
    __builtin_amdgcn_s_barrier();

    bf16x8 bfr[2][4];
#pragma unroll
    for (int n = 0; n < 4; ++n) {
      bfr[0][n] = *(const bf16x8*)&lB[cur][(rB + n * 16) * 64 + cx0];
      bfr[1][n] = *(const bf16x8*)&lB[cur][(rB + n * 16) * 64 + cx1];
    }
    __builtin_amdgcn_s_setprio(1);
#pragma unroll
    for (int m = 0; m < 4; ++m) {
      bf16x8 a0 = *(const bf16x8*)&lA[cur][(rA + m * 16) * 64 + cx0];
      bf16x8 a1 = *(const bf16x8*)&lA[cur][(rA + m * 16) * 64 + cx1];
#pragma unroll
      for (int n = 0; n < 4; ++n) {
        acc[m][n] = __builtin_amdgcn_mfma_f32_16x16x32_bf16(a0, bfr[0][n], acc[m][n], 0, 0, 0);
        acc[m][n] = __builtin_amdgcn_mfma_f32_16x16x32_bf16(a1, bfr[1][n], acc[m][n], 0, 0, 0);
      }
      accd[m] = __builtin_amdgcn_mfma_f32_16x16x32_bf16(a0, ones, accd[m], 0, 0, 0);
      accd[m] = __builtin_amdgcn_mfma_f32_16x16x32_bf16(a1, ones, accd[m], 0, 0, 0);
    }
    __builtin_amdgcn_s_setprio(0);
    __builtin_amdgcn_s_barrier();
    cur ^= 1;
  }
#undef STAGE

  float* ob = out + (size_t)b * SEQ * DIM;
#pragma unroll
  for (int m = 0; m < 4; ++m) {
#pragma unroll
    for (int j = 0; j < 4; ++j) {
      const int q  = q0 + wr * 64 + m * 16 + (lane >> 4) * 4 + j;
      const float sc = 1.0f / (accd[m][j] + EPS_K);
#pragma unroll
      for (int n = 0; n < 4; ++n) {
        const int d = d0 + wc * 64 + n * 16 + (lane & 15);
        ob[(size_t)q * DIM + d] = acc[m][n][j] * sc;
      }
    }
  }
}

// ---------------------------------------------------------------------------
extern "C" void kernel_launch(void* const* d_in, const int* in_sizes, int n_in,
                              void* d_out, int out_size, void* d_ws, size_t ws_size,
                              hipStream_t stream) {
  (void)in_sizes; (void)n_in; (void)out_size; (void)ws_size;
  const float* A    = (const float*)d_in[0];
  const int*   mask = (const int*)d_in[1];
  float*       out  = (float*)d_out;

  char* ws = (char*)d_ws;
  const size_t NB_AB = (size_t)BATCH * SEQ * DIM * 2;
  const size_t NB_AT = NB_AB;
  uint16_t* ab = (uint16_t*)(ws);
  uint16_t* at = (uint16_t*)(ws + NB_AB);
  uint16_t* P  = (uint16_t*)(ws + NB_AB + NB_AT);

  convert_kernel<<<dim3(DIM / 64, SEQ / 64, BATCH), dim3(256), 0, stream>>>(A, ab, at);
  scores_kernel<<<dim3(32 * BATCH), dim3(512), 0, stream>>>(ab, mask, P);
  out_kernel<<<dim3(24 * BATCH), dim3(512), 0, stream>>>(P, at, out);
}